// Round 10
// baseline (549.585 us; speedup 1.0000x reference)
//
#include <hip/hip_runtime.h>

// Dense dilated KNN graph. B=2, C=64, N=8192, k_total=18, keep ::2 -> 9.
// r10: separate hi/lo bf16 LDS tiles (direct b128 MFMA frags, no unpack),
// positive-float keys (C-init (sq+2)/2, A=-Q -> raw-bit monotone), 4-way
// part split (1024 blocks, 4/CU, 33KB LDS, in-place merge in pp).
// ws: ptsn [B][N][64] f32 (4MB) | sqnp f32 (64KB) | cand u16 [B*N][80] (2.6MB)

#define NPTS  8192
#define CHN   64
#define NB    2
#define KF    18
#define KC    8      // per-(row,stream) candidate list depth
#define KM    20     // per-part merged candidates
#define KOUT  9
#define NPART 4
#define TPB   32     // tiles per part

typedef unsigned u32;
typedef unsigned short u16;
typedef unsigned long long u64;
typedef __attribute__((ext_vector_type(4))) unsigned u32x4;
typedef __attribute__((ext_vector_type(8))) short bf16x8;
typedef __attribute__((ext_vector_type(4))) float f32x4;

__device__ __forceinline__ u32 umin32(u32 a, u32 b) { return a < b ? a : b; }
__device__ __forceinline__ u32 umax32(u32 a, u32 b) { return a > b ? a : b; }

// split float4 -> 2 u32 of adjacent-element hi-bf16s + 2 u32 of lo-bf16s
__device__ __forceinline__ void split4(float4 v, u32* h, u32* l) {
  const u32 b0 = __float_as_uint(v.x), b1 = __float_as_uint(v.y);
  const u32 b2 = __float_as_uint(v.z), b3 = __float_as_uint(v.w);
  const float l0 = v.x - __uint_as_float(b0 & 0xffff0000u);
  const float l1 = v.y - __uint_as_float(b1 & 0xffff0000u);
  const float l2 = v.z - __uint_as_float(b2 & 0xffff0000u);
  const float l3 = v.w - __uint_as_float(b3 & 0xffff0000u);
  h[0] = __builtin_amdgcn_perm(b1, b0, 0x07060302u);
  h[1] = __builtin_amdgcn_perm(b3, b2, 0x07060302u);
  l[0] = __builtin_amdgcn_perm(__float_as_uint(l1), __float_as_uint(l0), 0x07060302u);
  l[1] = __builtin_amdgcn_perm(__float_as_uint(l3), __float_as_uint(l2), 0x07060302u);
}

__device__ __forceinline__ u32 mono32(float f) {
  const u32 u = __float_as_uint(f);
  const u32 s = (u32)((int)u >> 31);
  return u ^ (s | 0x80000000u);
}

// branchless sorted-ascending top-K insert: 2 VALU per stage
template <int KK>
__device__ __forceinline__ void insmm(u32 key, u32 (&d)[KK]) {
#pragma unroll
  for (int k = KK - 1; k >= 1; --k) d[k] = umax32(d[k - 1], umin32(d[k], key));
  d[0] = umin32(d[0], key);
}

template <int KK>
__device__ __forceinline__ void ins64(u64 key, u64 (&d)[KK]) {
  if (key < d[KK - 1]) {
#pragma unroll
    for (int k = KK - 1; k >= 1; --k) {
      const bool up = d[k - 1] > key;
      const bool here = (!up) && (d[k] > key);
      d[k] = up ? d[k - 1] : (here ? key : d[k]);
    }
    if (d[0] > key) d[0] = key;
  }
}

// ---------------- kernel 1: np-faithful normalize + pairwise sq ----------------
__global__ __launch_bounds__(128) void prep_kernel(
    const float* __restrict__ x, float* __restrict__ pts, float* __restrict__ sq) {
  const int b = blockIdx.x >> 6;
  const int n = ((blockIdx.x & 63) << 7) + threadIdx.x;
  const float* __restrict__ xb = x + (size_t)b * CHN * NPTS + n;
  float v[CHN];
  float ss = 0.f;
#pragma unroll
  for (int c = 0; c < CHN; ++c) {
    v[c] = xb[(size_t)c * NPTS];
    ss = __fadd_rn(ss, __fmul_rn(v[c], v[c]));
  }
  const float den = fmaxf(__fsqrt_rn(ss), 1e-12f);
#pragma unroll
  for (int c = 0; c < CHN; ++c) v[c] = __fdiv_rn(v[c], den);
  float r[8];
#pragma unroll
  for (int j = 0; j < 8; ++j) r[j] = __fmul_rn(v[j], v[j]);
#pragma unroll
  for (int blk = 1; blk < 8; ++blk)
#pragma unroll
    for (int j = 0; j < 8; ++j)
      r[j] = __fadd_rn(r[j], __fmul_rn(v[8 * blk + j], v[8 * blk + j]));
  const float t0 = __fadd_rn(r[0], r[1]);
  const float t1 = __fadd_rn(r[2], r[3]);
  const float t2 = __fadd_rn(r[4], r[5]);
  const float t3 = __fadd_rn(r[6], r[7]);
  sq[(b << 13) + n] = __fadd_rn(__fadd_rn(t0, t1), __fadd_rn(t2, t3));
  float4* dst = (float4*)(pts + (size_t)(b * NPTS + n) * CHN);
#pragma unroll
  for (int u = 0; u < 16; ++u)
    dst[u] = make_float4(v[4 * u], v[4 * u + 1], v[4 * u + 2], v[4 * u + 3]);
}

// ---------------- kernel 2: MFMA GEMM + reg-select + in-place merge ----------------
__global__ __launch_bounds__(256, 4) void knn_part_kernel(
    const float* __restrict__ pts, const float* __restrict__ sq,
    u16* __restrict__ cand) {
  // pp[buf]: hi tile = [0..2047] (64 rows x 32 u32), lo tile = [2048..4095]
  __shared__ __align__(16) u32 pp[2][4096];
  __shared__ float sqp[2][64];

  const int tid = threadIdx.x;
  const int vb = ((blockIdx.x & 7) << 7) + (blockIdx.x >> 3);  // 1024 = 8*128
  const int part = vb >> 8;                  // 0..3
  const int w = vb & 255;
  const int b = w >> 7;
  const int qbase = (w & 127) << 6;
  const int t_lo = part << 5;                // *TPB
  const float* __restrict__ pb = pts + ((size_t)b << 19);
  const float* __restrict__ sqb = sq + (b << 13);

  const int sr = tid >> 2, ssub = tid & 3;   // staging mapping
  const int lane = tid & 63, wid = tid >> 6; // MFMA mapping
  const int qoff = (wid & 1) << 5;
  const int moff = (wid >> 1) << 5;
  const int l15 = lane & 15;
  const int h4 = lane >> 4;
  const int sw = l15 & 7;                    // read-swizzle source (=row&7)

  // ---- prologue: Q (negated) -> pp[1], P(t_lo) -> pp[0], sqp[0]
  {
    const float4* qsrc =
        (const float4*)(pb + ((size_t)(qbase + sr) << 6) + (ssub << 4));
    const float4* psrc =
        (const float4*)(pb + ((size_t)((t_lo << 6) + sr) << 6) + (ssub << 4));
    u32 qh[8], ql[8], ph[8], pl[8];
#pragma unroll
    for (int q = 0; q < 4; ++q) {
      float4 qv = qsrc[q];
      qv.x = -qv.x; qv.y = -qv.y; qv.z = -qv.z; qv.w = -qv.w;
      split4(qv, qh + 2 * q, ql + 2 * q);
      split4(psrc[q], ph + 2 * q, pl + 2 * q);
    }
    const int qa = sr * 32 + (((ssub << 1) ^ (sr & 7)) << 2);
    const int qb2 = sr * 32 + ((((ssub << 1) + 1) ^ (sr & 7)) << 2);
    *(u32x4*)(pp[1] + qa) = *(u32x4*)qh;
    *(u32x4*)(pp[1] + qb2) = *(u32x4*)(qh + 4);
    *(u32x4*)(pp[1] + 2048 + qa) = *(u32x4*)ql;
    *(u32x4*)(pp[1] + 2048 + qb2) = *(u32x4*)(ql + 4);
    *(u32x4*)(pp[0] + qa) = *(u32x4*)ph;
    *(u32x4*)(pp[0] + qb2) = *(u32x4*)(ph + 4);
    *(u32x4*)(pp[0] + 2048 + qa) = *(u32x4*)pl;
    *(u32x4*)(pp[0] + 2048 + qb2) = *(u32x4*)(pl + 4);
    if (tid < 64) sqp[0][tid] = (sqb[(t_lo << 6) + tid] + 2.f) * 0.5f;
  }
  __syncthreads();

  // ---- build A fragments from pp[1] (negated Q), then free pp[1]
  bf16x8 ah[2][2], al[2][2];
#pragma unroll
  for (int g = 0; g < 2; ++g)
#pragma unroll
    for (int s = 0; s < 2; ++s) {
      const int row = qoff + (g << 4) + l15;
      const int off = row * 32 + ((((s << 2) + h4) ^ sw) << 2);
      ah[g][s] = __builtin_bit_cast(bf16x8, *(const u32x4*)(pp[1] + off));
      al[g][s] = __builtin_bit_cast(bf16x8, *(const u32x4*)(pp[1] + 2048 + off));
    }
  __syncthreads();

  // per-lane candidate lists (static indexing only)
  u32 d[2][4][KC];
#pragma unroll
  for (int g = 0; g < 2; ++g)
#pragma unroll
    for (int i = 0; i < 4; ++i)
#pragma unroll
      for (int k = 0; k < KC; ++k) d[g][i][k] = 0xffffffffu;

  for (int tau = 0; tau < TPB; ++tau) {
    const int cur = tau & 1;
    float4 st[4];
    float sqv = 0.f;
    const bool more = (tau + 1) < TPB;
    if (more) {   // issue next-tile global loads early
      const float4* nsrc = (const float4*)(
          pb + ((size_t)(t_lo + tau + 1) << 12) + (sr << 6) + (ssub << 4));
#pragma unroll
      for (int q = 0; q < 4; ++q) st[q] = nsrc[q];
      if (tid < 64) sqv = sqb[((t_lo + tau + 1) << 6) + tid];
    }
    // ---- MFMA: acc = (sq_m+2)/2 - q.p  (positive, order = dist) + select
    const u32* ppc = pp[cur];
#pragma unroll
    for (int f = 0; f < 2; ++f) {
      const int m_l = moff + (f << 4) + l15;
      const float sqm = sqp[cur][m_l];
      f32x4 acc[2];
      acc[0] = (f32x4){sqm, sqm, sqm, sqm};
      acc[1] = acc[0];
#pragma unroll
      for (int s = 0; s < 2; ++s) {
        const u32* hb = ppc + m_l * 32 + ((((s << 2) + h4) ^ sw) << 2);
        const bf16x8 bh = __builtin_bit_cast(bf16x8, *(const u32x4*)hb);
        const bf16x8 bl = __builtin_bit_cast(bf16x8, *(const u32x4*)(hb + 2048));
        acc[0] = __builtin_amdgcn_mfma_f32_16x16x32_bf16(ah[0][s], bh, acc[0], 0, 0, 0);
        acc[1] = __builtin_amdgcn_mfma_f32_16x16x32_bf16(ah[1][s], bh, acc[1], 0, 0, 0);
        acc[0] = __builtin_amdgcn_mfma_f32_16x16x32_bf16(al[0][s], bh, acc[0], 0, 0, 0);
        acc[1] = __builtin_amdgcn_mfma_f32_16x16x32_bf16(al[1][s], bh, acc[1], 0, 0, 0);
        acc[0] = __builtin_amdgcn_mfma_f32_16x16x32_bf16(ah[0][s], bl, acc[0], 0, 0, 0);
        acc[1] = __builtin_amdgcn_mfma_f32_16x16x32_bf16(ah[1][s], bl, acc[1], 0, 0, 0);
      }
      const u32 lidx = (u32)((tau << 6) + m_l);
#pragma unroll
      for (int g = 0; g < 2; ++g)
#pragma unroll
        for (int i = 0; i < 4; ++i) {
          const u32 key = (__float_as_uint(acc[g][i]) & 0xfffff000u) | lidx;
          insmm<KC>(key, d[g][i]);
        }
    }
    // ---- split-pack + write next tile into pp[cur^1]
    if (more) {
      u32 hh[8], ll[8];
#pragma unroll
      for (int q = 0; q < 4; ++q) split4(st[q], hh + 2 * q, ll + 2 * q);
      u32* wp = pp[cur ^ 1];
      const int qa = sr * 32 + (((ssub << 1) ^ (sr & 7)) << 2);
      const int qb2 = sr * 32 + ((((ssub << 1) + 1) ^ (sr & 7)) << 2);
      *(u32x4*)(wp + qa) = *(u32x4*)hh;
      *(u32x4*)(wp + qb2) = *(u32x4*)(hh + 4);
      *(u32x4*)(wp + 2048 + qa) = *(u32x4*)ll;
      *(u32x4*)(wp + 2048 + qb2) = *(u32x4*)(ll + 4);
      if (tid < 64) sqp[cur ^ 1][tid] = (sqv + 2.f) * 0.5f;
    }
    __syncthreads();   // the ONE barrier per tile
  }

  // ---- in-place 3-level merge in pp (two 32-row chunks)
  u32* mg = &pp[0][0];                       // 8192 u32
  const int stream = ((wid >> 1) << 4) + l15;
  const int rcb = ((wid & 1) << 4) + (h4 << 2);
#pragma unroll
  for (int chunk = 0; chunk < 2; ++chunk) {
    // dump: [rowc][stream][8]
#pragma unroll
    for (int i = 0; i < 4; ++i) {
      u32* wr = mg + ((rcb + i) * 32 + stream) * 8;
      u32x4 a, c;
      a.x = d[chunk][i][0]; a.y = d[chunk][i][1];
      a.z = d[chunk][i][2]; a.w = d[chunk][i][3];
      c.x = d[chunk][i][4]; c.y = d[chunk][i][5];
      c.z = d[chunk][i][6]; c.w = d[chunk][i][7];
      *(u32x4*)wr = a;
      *(u32x4*)(wr + 4) = c;
    }
    __syncthreads();
    // M1: (rowc, oct): 4 streams x 8 -> top-14, write back in-place
    {
      const int rowc = tid >> 3, oct = tid & 7;
      u32* base = mg + rowc * 256 + oct * 32;
      u32 m1[14];
#pragma unroll
      for (int k = 0; k < 14; ++k) m1[k] = 0xffffffffu;
#pragma unroll
      for (int j = 0; j < 8; ++j) {
        const u32x4 k4 = *(const u32x4*)(base + (j << 2));
        insmm<14>(k4.x, m1);
        insmm<14>(k4.y, m1);
        insmm<14>(k4.z, m1);
        insmm<14>(k4.w, m1);
      }
#pragma unroll
      for (int k = 0; k < 14; ++k) base[k] = m1[k];
    }
    __syncthreads();
    // M2: (rowc, half): 4 octs x 14 -> top-20, write in-place at half base
    if (tid < 64) {
      const int rowc = tid >> 1, half = tid & 1;
      u32* rb = mg + rowc * 256 + half * 128;
      u32 m2[KM];
#pragma unroll
      for (int k = 0; k < KM; ++k) m2[k] = 0xffffffffu;
#pragma unroll
      for (int o = 0; o < 4; ++o) {
        const u32* p = rb + o * 32;
        for (int j = 0; j < 14; ++j) insmm<KM>(p[j], m2);
      }
#pragma unroll
      for (int k = 0; k < KM; ++k) rb[k] = m2[k];
    }
    __syncthreads();
    // M3: rowc: 2 x 20 -> top-20 -> cand (u16 global idx)
    if (tid < 32) {
      u32 m3[KM];
#pragma unroll
      for (int k = 0; k < KM; ++k) m3[k] = 0xffffffffu;
      const u32* p0 = mg + tid * 256;
      for (int j = 0; j < KM; ++j) insmm<KM>(p0[j], m3);
      const u32* p1 = mg + tid * 256 + 128;
      for (int j = 0; j < KM; ++j) insmm<KM>(p1[j], m3);
      const int row = ((tid >> 4) << 5) + (chunk << 4) + (tid & 15);
      const int rg = (b << 13) + qbase + row;
      u16* cw = cand + (size_t)rg * (NPART * KM) + part * KM;
#pragma unroll
      for (int k = 0; k < KM; ++k)
        cw[k] = (u16)((part << 11) + (m3[k] & 0xfffu));
    }
    __syncthreads();
  }
}

// ---------------- kernel 3: bit-exact np-fp32 rescore + output ----------------
__global__ __launch_bounds__(256) void finalize_kernel(
    const float* __restrict__ pts, const float* __restrict__ sq,
    const u16* __restrict__ cand, int* __restrict__ out) {
  __shared__ u64 ex[64 * 80];
  const int tid = threadIdx.x;
  const int rl = tid >> 2, sub = tid & 3;
  const int row = blockIdx.x * 64 + rl;          // 0..16383
  const int b = row >> 13;
  const float* __restrict__ qrow = pts + ((size_t)row << 6);
  const float sqn = sq[row];
  const u16* __restrict__ cr = cand + (size_t)row * 80 + sub * 20;
  for (int j = 0; j < 20; ++j) {
    const int ix = cr[j];
    const float* __restrict__ pv = pts + ((size_t)((b << 13) + ix) << 6);
    // einsum replica: c ascending, rounded mul + rounded add, init 0, no fma
    float dot = 0.f;
#pragma unroll
    for (int c = 0; c < CHN; ++c)
      dot = __fadd_rn(dot, __fmul_rn(qrow[c], pv[c]));
    const float dist =
        __fadd_rn(__fsub_rn(sqn, __fmul_rn(2.0f, dot)), sq[(b << 13) + ix]);
    ex[rl * 80 + sub * 20 + j] = ((u64)mono32(dist) << 32) | (unsigned)ix;
  }
  __syncthreads();
  if (tid < 64) {
    u64 m18[KF];
#pragma unroll
    for (int k = 0; k < KF; ++k) m18[k] = ~0ull;
    for (int j = 0; j < 80; ++j) ins64<KF>(ex[tid * 80 + j], m18);
    const int row2 = blockIdx.x * 64 + tid;
    const int n2 = row2 & 8191;
    int* o0 = out + (size_t)row2 * KOUT;
    int* o1 = o0 + NB * NPTS * KOUT;
#pragma unroll
    for (int k = 0; k < KOUT; ++k) {
      o0[k] = (int)(m18[2 * k] & 0xffffffffu);
      o1[k] = n2;
    }
  }
}

// ---------------- launcher ----------------
extern "C" void kernel_launch(void* const* d_in, const int* in_sizes, int n_in,
                              void* d_out, int out_size, void* d_ws, size_t ws_size,
                              hipStream_t stream) {
  const float* x = (const float*)d_in[0];
  float* pts = (float*)d_ws;                           // 4 MB
  float* sqg = pts + (size_t)NB * NPTS * CHN;          // 64 KB
  u16* cand = (u16*)(sqg + NB * NPTS);                 // 2.62 MB
  int* out = (int*)d_out;
  prep_kernel<<<dim3(128), dim3(128), 0, stream>>>(x, pts, sqg);
  knn_part_kernel<<<dim3(1024), dim3(256), 0, stream>>>(pts, sqg, cand);
  finalize_kernel<<<dim3(256), dim3(256), 0, stream>>>(pts, sqg, cand, out);
}

// Round 11
// 241.742 us; speedup vs baseline: 2.2734x; 2.2734x over previous
//
#include <hip/hip_runtime.h>

// Dense dilated KNN graph. B=2, C=64, N=8192, k_total=18, keep ::2 -> 9.
// r11 = r10 with __launch_bounds__(256,3): r10's (256,4) cut the VGPR budget
// to 128 < ~140 live -> candidate lists spilled to scratch (904MB FETCH,
// 574MB WRITE, 2.3x regression). Budget 170 removes the spill; all r10
// improvements kept (hi/lo split tiles, positive-bit keys, 4-part, in-place
// merge, 33KB LDS).
// ws: ptsn [B][N][64] f32 (4MB) | sqnp f32 (64KB) | cand u16 [B*N][80] (2.6MB)

#define NPTS  8192
#define CHN   64
#define NB    2
#define KF    18
#define KC    8      // per-(row,stream) candidate list depth
#define KM    20     // per-part merged candidates
#define KOUT  9
#define NPART 4
#define TPB   32     // tiles per part

typedef unsigned u32;
typedef unsigned short u16;
typedef unsigned long long u64;
typedef __attribute__((ext_vector_type(4))) unsigned u32x4;
typedef __attribute__((ext_vector_type(8))) short bf16x8;
typedef __attribute__((ext_vector_type(4))) float f32x4;

__device__ __forceinline__ u32 umin32(u32 a, u32 b) { return a < b ? a : b; }
__device__ __forceinline__ u32 umax32(u32 a, u32 b) { return a > b ? a : b; }

// split float4 -> 2 u32 of adjacent-element hi-bf16s + 2 u32 of lo-bf16s
__device__ __forceinline__ void split4(float4 v, u32* h, u32* l) {
  const u32 b0 = __float_as_uint(v.x), b1 = __float_as_uint(v.y);
  const u32 b2 = __float_as_uint(v.z), b3 = __float_as_uint(v.w);
  const float l0 = v.x - __uint_as_float(b0 & 0xffff0000u);
  const float l1 = v.y - __uint_as_float(b1 & 0xffff0000u);
  const float l2 = v.z - __uint_as_float(b2 & 0xffff0000u);
  const float l3 = v.w - __uint_as_float(b3 & 0xffff0000u);
  h[0] = __builtin_amdgcn_perm(b1, b0, 0x07060302u);
  h[1] = __builtin_amdgcn_perm(b3, b2, 0x07060302u);
  l[0] = __builtin_amdgcn_perm(__float_as_uint(l1), __float_as_uint(l0), 0x07060302u);
  l[1] = __builtin_amdgcn_perm(__float_as_uint(l3), __float_as_uint(l2), 0x07060302u);
}

__device__ __forceinline__ u32 mono32(float f) {
  const u32 u = __float_as_uint(f);
  const u32 s = (u32)((int)u >> 31);
  return u ^ (s | 0x80000000u);
}

// branchless sorted-ascending top-K insert: 2 VALU per stage
template <int KK>
__device__ __forceinline__ void insmm(u32 key, u32 (&d)[KK]) {
#pragma unroll
  for (int k = KK - 1; k >= 1; --k) d[k] = umax32(d[k - 1], umin32(d[k], key));
  d[0] = umin32(d[0], key);
}

template <int KK>
__device__ __forceinline__ void ins64(u64 key, u64 (&d)[KK]) {
  if (key < d[KK - 1]) {
#pragma unroll
    for (int k = KK - 1; k >= 1; --k) {
      const bool up = d[k - 1] > key;
      const bool here = (!up) && (d[k] > key);
      d[k] = up ? d[k - 1] : (here ? key : d[k]);
    }
    if (d[0] > key) d[0] = key;
  }
}

// ---------------- kernel 1: np-faithful normalize + pairwise sq ----------------
__global__ __launch_bounds__(128) void prep_kernel(
    const float* __restrict__ x, float* __restrict__ pts, float* __restrict__ sq) {
  const int b = blockIdx.x >> 6;
  const int n = ((blockIdx.x & 63) << 7) + threadIdx.x;
  const float* __restrict__ xb = x + (size_t)b * CHN * NPTS + n;
  float v[CHN];
  float ss = 0.f;
#pragma unroll
  for (int c = 0; c < CHN; ++c) {
    v[c] = xb[(size_t)c * NPTS];
    ss = __fadd_rn(ss, __fmul_rn(v[c], v[c]));
  }
  const float den = fmaxf(__fsqrt_rn(ss), 1e-12f);
#pragma unroll
  for (int c = 0; c < CHN; ++c) v[c] = __fdiv_rn(v[c], den);
  float r[8];
#pragma unroll
  for (int j = 0; j < 8; ++j) r[j] = __fmul_rn(v[j], v[j]);
#pragma unroll
  for (int blk = 1; blk < 8; ++blk)
#pragma unroll
    for (int j = 0; j < 8; ++j)
      r[j] = __fadd_rn(r[j], __fmul_rn(v[8 * blk + j], v[8 * blk + j]));
  const float t0 = __fadd_rn(r[0], r[1]);
  const float t1 = __fadd_rn(r[2], r[3]);
  const float t2 = __fadd_rn(r[4], r[5]);
  const float t3 = __fadd_rn(r[6], r[7]);
  sq[(b << 13) + n] = __fadd_rn(__fadd_rn(t0, t1), __fadd_rn(t2, t3));
  float4* dst = (float4*)(pts + (size_t)(b * NPTS + n) * CHN);
#pragma unroll
  for (int u = 0; u < 16; ++u)
    dst[u] = make_float4(v[4 * u], v[4 * u + 1], v[4 * u + 2], v[4 * u + 3]);
}

// ---------------- kernel 2: MFMA GEMM + reg-select + in-place merge ----------------
__global__ __launch_bounds__(256, 3) void knn_part_kernel(
    const float* __restrict__ pts, const float* __restrict__ sq,
    u16* __restrict__ cand) {
  // pp[buf]: hi tile = [0..2047] (64 rows x 32 u32), lo tile = [2048..4095]
  __shared__ __align__(16) u32 pp[2][4096];
  __shared__ float sqp[2][64];

  const int tid = threadIdx.x;
  const int vb = ((blockIdx.x & 7) << 7) + (blockIdx.x >> 3);  // 1024 = 8*128
  const int part = vb >> 8;                  // 0..3
  const int w = vb & 255;
  const int b = w >> 7;
  const int qbase = (w & 127) << 6;
  const int t_lo = part << 5;                // *TPB
  const float* __restrict__ pb = pts + ((size_t)b << 19);
  const float* __restrict__ sqb = sq + (b << 13);

  const int sr = tid >> 2, ssub = tid & 3;   // staging mapping
  const int lane = tid & 63, wid = tid >> 6; // MFMA mapping
  const int qoff = (wid & 1) << 5;
  const int moff = (wid >> 1) << 5;
  const int l15 = lane & 15;
  const int h4 = lane >> 4;
  const int sw = l15 & 7;                    // read-swizzle source (=row&7)

  // ---- prologue: Q (negated) -> pp[1], P(t_lo) -> pp[0], sqp[0]
  {
    const float4* qsrc =
        (const float4*)(pb + ((size_t)(qbase + sr) << 6) + (ssub << 4));
    const float4* psrc =
        (const float4*)(pb + ((size_t)((t_lo << 6) + sr) << 6) + (ssub << 4));
    u32 qh[8], ql[8], ph[8], pl[8];
#pragma unroll
    for (int q = 0; q < 4; ++q) {
      float4 qv = qsrc[q];
      qv.x = -qv.x; qv.y = -qv.y; qv.z = -qv.z; qv.w = -qv.w;
      split4(qv, qh + 2 * q, ql + 2 * q);
      split4(psrc[q], ph + 2 * q, pl + 2 * q);
    }
    const int qa = sr * 32 + (((ssub << 1) ^ (sr & 7)) << 2);
    const int qb2 = sr * 32 + ((((ssub << 1) + 1) ^ (sr & 7)) << 2);
    *(u32x4*)(pp[1] + qa) = *(u32x4*)qh;
    *(u32x4*)(pp[1] + qb2) = *(u32x4*)(qh + 4);
    *(u32x4*)(pp[1] + 2048 + qa) = *(u32x4*)ql;
    *(u32x4*)(pp[1] + 2048 + qb2) = *(u32x4*)(ql + 4);
    *(u32x4*)(pp[0] + qa) = *(u32x4*)ph;
    *(u32x4*)(pp[0] + qb2) = *(u32x4*)(ph + 4);
    *(u32x4*)(pp[0] + 2048 + qa) = *(u32x4*)pl;
    *(u32x4*)(pp[0] + 2048 + qb2) = *(u32x4*)(pl + 4);
    if (tid < 64) sqp[0][tid] = (sqb[(t_lo << 6) + tid] + 2.f) * 0.5f;
  }
  __syncthreads();

  // ---- build A fragments from pp[1] (negated Q), then free pp[1]
  bf16x8 ah[2][2], al[2][2];
#pragma unroll
  for (int g = 0; g < 2; ++g)
#pragma unroll
    for (int s = 0; s < 2; ++s) {
      const int row = qoff + (g << 4) + l15;
      const int off = row * 32 + ((((s << 2) + h4) ^ sw) << 2);
      ah[g][s] = __builtin_bit_cast(bf16x8, *(const u32x4*)(pp[1] + off));
      al[g][s] = __builtin_bit_cast(bf16x8, *(const u32x4*)(pp[1] + 2048 + off));
    }
  __syncthreads();

  // per-lane candidate lists (static indexing only)
  u32 d[2][4][KC];
#pragma unroll
  for (int g = 0; g < 2; ++g)
#pragma unroll
    for (int i = 0; i < 4; ++i)
#pragma unroll
      for (int k = 0; k < KC; ++k) d[g][i][k] = 0xffffffffu;

  for (int tau = 0; tau < TPB; ++tau) {
    const int cur = tau & 1;
    float4 st[4];
    float sqv = 0.f;
    const bool more = (tau + 1) < TPB;
    if (more) {   // issue next-tile global loads early
      const float4* nsrc = (const float4*)(
          pb + ((size_t)(t_lo + tau + 1) << 12) + (sr << 6) + (ssub << 4));
#pragma unroll
      for (int q = 0; q < 4; ++q) st[q] = nsrc[q];
      if (tid < 64) sqv = sqb[((t_lo + tau + 1) << 6) + tid];
    }
    // ---- MFMA: acc = (sq_m+2)/2 - q.p  (positive, order = dist) + select
    const u32* ppc = pp[cur];
#pragma unroll
    for (int f = 0; f < 2; ++f) {
      const int m_l = moff + (f << 4) + l15;
      const float sqm = sqp[cur][m_l];
      f32x4 acc[2];
      acc[0] = (f32x4){sqm, sqm, sqm, sqm};
      acc[1] = acc[0];
#pragma unroll
      for (int s = 0; s < 2; ++s) {
        const u32* hb = ppc + m_l * 32 + ((((s << 2) + h4) ^ sw) << 2);
        const bf16x8 bh = __builtin_bit_cast(bf16x8, *(const u32x4*)hb);
        const bf16x8 bl = __builtin_bit_cast(bf16x8, *(const u32x4*)(hb + 2048));
        acc[0] = __builtin_amdgcn_mfma_f32_16x16x32_bf16(ah[0][s], bh, acc[0], 0, 0, 0);
        acc[1] = __builtin_amdgcn_mfma_f32_16x16x32_bf16(ah[1][s], bh, acc[1], 0, 0, 0);
        acc[0] = __builtin_amdgcn_mfma_f32_16x16x32_bf16(al[0][s], bh, acc[0], 0, 0, 0);
        acc[1] = __builtin_amdgcn_mfma_f32_16x16x32_bf16(al[1][s], bh, acc[1], 0, 0, 0);
        acc[0] = __builtin_amdgcn_mfma_f32_16x16x32_bf16(ah[0][s], bl, acc[0], 0, 0, 0);
        acc[1] = __builtin_amdgcn_mfma_f32_16x16x32_bf16(ah[1][s], bl, acc[1], 0, 0, 0);
      }
      const u32 lidx = (u32)((tau << 6) + m_l);
#pragma unroll
      for (int g = 0; g < 2; ++g)
#pragma unroll
        for (int i = 0; i < 4; ++i) {
          const u32 key = (__float_as_uint(acc[g][i]) & 0xfffff000u) | lidx;
          insmm<KC>(key, d[g][i]);
        }
    }
    // ---- split-pack + write next tile into pp[cur^1]
    if (more) {
      u32 hh[8], ll[8];
#pragma unroll
      for (int q = 0; q < 4; ++q) split4(st[q], hh + 2 * q, ll + 2 * q);
      u32* wp = pp[cur ^ 1];
      const int qa = sr * 32 + (((ssub << 1) ^ (sr & 7)) << 2);
      const int qb2 = sr * 32 + ((((ssub << 1) + 1) ^ (sr & 7)) << 2);
      *(u32x4*)(wp + qa) = *(u32x4*)hh;
      *(u32x4*)(wp + qb2) = *(u32x4*)(hh + 4);
      *(u32x4*)(wp + 2048 + qa) = *(u32x4*)ll;
      *(u32x4*)(wp + 2048 + qb2) = *(u32x4*)(ll + 4);
      if (tid < 64) sqp[cur ^ 1][tid] = (sqv + 2.f) * 0.5f;
    }
    __syncthreads();   // the ONE barrier per tile
  }

  // ---- in-place 3-level merge in pp (two 32-row chunks)
  u32* mg = &pp[0][0];                       // 8192 u32
  const int stream = ((wid >> 1) << 4) + l15;
  const int rcb = ((wid & 1) << 4) + (h4 << 2);
#pragma unroll
  for (int chunk = 0; chunk < 2; ++chunk) {
    // dump: [rowc][stream][8]
#pragma unroll
    for (int i = 0; i < 4; ++i) {
      u32* wr = mg + ((rcb + i) * 32 + stream) * 8;
      u32x4 a, c;
      a.x = d[chunk][i][0]; a.y = d[chunk][i][1];
      a.z = d[chunk][i][2]; a.w = d[chunk][i][3];
      c.x = d[chunk][i][4]; c.y = d[chunk][i][5];
      c.z = d[chunk][i][6]; c.w = d[chunk][i][7];
      *(u32x4*)wr = a;
      *(u32x4*)(wr + 4) = c;
    }
    __syncthreads();
    // M1: (rowc, oct): 4 streams x 8 -> top-14, write back in-place
    {
      const int rowc = tid >> 3, oct = tid & 7;
      u32* base = mg + rowc * 256 + oct * 32;
      u32 m1[14];
#pragma unroll
      for (int k = 0; k < 14; ++k) m1[k] = 0xffffffffu;
#pragma unroll
      for (int j = 0; j < 8; ++j) {
        const u32x4 k4 = *(const u32x4*)(base + (j << 2));
        insmm<14>(k4.x, m1);
        insmm<14>(k4.y, m1);
        insmm<14>(k4.z, m1);
        insmm<14>(k4.w, m1);
      }
#pragma unroll
      for (int k = 0; k < 14; ++k) base[k] = m1[k];
    }
    __syncthreads();
    // M2: (rowc, half): 4 octs x 14 -> top-20, write in-place at half base
    if (tid < 64) {
      const int rowc = tid >> 1, half = tid & 1;
      u32* rb = mg + rowc * 256 + half * 128;
      u32 m2[KM];
#pragma unroll
      for (int k = 0; k < KM; ++k) m2[k] = 0xffffffffu;
#pragma unroll
      for (int o = 0; o < 4; ++o) {
        const u32* p = rb + o * 32;
        for (int j = 0; j < 14; ++j) insmm<KM>(p[j], m2);
      }
#pragma unroll
      for (int k = 0; k < KM; ++k) rb[k] = m2[k];
    }
    __syncthreads();
    // M3: rowc: 2 x 20 -> top-20 -> cand (u16 global idx)
    if (tid < 32) {
      u32 m3[KM];
#pragma unroll
      for (int k = 0; k < KM; ++k) m3[k] = 0xffffffffu;
      const u32* p0 = mg + tid * 256;
      for (int j = 0; j < KM; ++j) insmm<KM>(p0[j], m3);
      const u32* p1 = mg + tid * 256 + 128;
      for (int j = 0; j < KM; ++j) insmm<KM>(p1[j], m3);
      const int row = ((tid >> 4) << 5) + (chunk << 4) + (tid & 15);
      const int rg = (b << 13) + qbase + row;
      u16* cw = cand + (size_t)rg * (NPART * KM) + part * KM;
#pragma unroll
      for (int k = 0; k < KM; ++k)
        cw[k] = (u16)((part << 11) + (m3[k] & 0xfffu));
    }
    __syncthreads();
  }
}

// ---------------- kernel 3: bit-exact np-fp32 rescore + output ----------------
__global__ __launch_bounds__(256) void finalize_kernel(
    const float* __restrict__ pts, const float* __restrict__ sq,
    const u16* __restrict__ cand, int* __restrict__ out) {
  __shared__ u64 ex[64 * 80];
  const int tid = threadIdx.x;
  const int rl = tid >> 2, sub = tid & 3;
  const int row = blockIdx.x * 64 + rl;          // 0..16383
  const int b = row >> 13;
  const float* __restrict__ qrow = pts + ((size_t)row << 6);
  const float sqn = sq[row];
  const u16* __restrict__ cr = cand + (size_t)row * 80 + sub * 20;
  for (int j = 0; j < 20; ++j) {
    const int ix = cr[j];
    const float* __restrict__ pv = pts + ((size_t)((b << 13) + ix) << 6);
    // einsum replica: c ascending, rounded mul + rounded add, init 0, no fma
    float dot = 0.f;
#pragma unroll
    for (int c = 0; c < CHN; ++c)
      dot = __fadd_rn(dot, __fmul_rn(qrow[c], pv[c]));
    const float dist =
        __fadd_rn(__fsub_rn(sqn, __fmul_rn(2.0f, dot)), sq[(b << 13) + ix]);
    ex[rl * 80 + sub * 20 + j] = ((u64)mono32(dist) << 32) | (unsigned)ix;
  }
  __syncthreads();
  if (tid < 64) {
    u64 m18[KF];
#pragma unroll
    for (int k = 0; k < KF; ++k) m18[k] = ~0ull;
    for (int j = 0; j < 80; ++j) ins64<KF>(ex[tid * 80 + j], m18);
    const int row2 = blockIdx.x * 64 + tid;
    const int n2 = row2 & 8191;
    int* o0 = out + (size_t)row2 * KOUT;
    int* o1 = o0 + NB * NPTS * KOUT;
#pragma unroll
    for (int k = 0; k < KOUT; ++k) {
      o0[k] = (int)(m18[2 * k] & 0xffffffffu);
      o1[k] = n2;
    }
  }
}

// ---------------- launcher ----------------
extern "C" void kernel_launch(void* const* d_in, const int* in_sizes, int n_in,
                              void* d_out, int out_size, void* d_ws, size_t ws_size,
                              hipStream_t stream) {
  const float* x = (const float*)d_in[0];
  float* pts = (float*)d_ws;                           // 4 MB
  float* sqg = pts + (size_t)NB * NPTS * CHN;          // 64 KB
  u16* cand = (u16*)(sqg + NB * NPTS);                 // 2.62 MB
  int* out = (int*)d_out;
  prep_kernel<<<dim3(128), dim3(128), 0, stream>>>(x, pts, sqg);
  knn_part_kernel<<<dim3(1024), dim3(256), 0, stream>>>(pts, sqg, cand);
  finalize_kernel<<<dim3(256), dim3(256), 0, stream>>>(pts, sqg, cand, out);
}